// Round 9
// baseline (162.567 us; speedup 1.0000x reference)
//
#include <hip/hip_runtime.h>

#define Hd 512
#define N2d 16
#define Rd 32
#define Ld 4096
#define NCHUNK 256
#define CLEN (Ld / NCHUNK)   // 16
#define NCH (Hd * N2d)       // 8192 chains

// ---------------------------------------------------------------------------
// Kernel 0: transpose dt_w[H][R] -> dt_wT[R][H].
// ---------------------------------------------------------------------------
__global__ __launch_bounds__(256) void k_tw(const float* __restrict__ dt_w,
                                            float* __restrict__ dt_wT) {
    int idx = blockIdx.x * 256 + threadIdx.x;
    int r = idx >> 9;
    int h = idx & 511;
    dt_wT[idx] = dt_w[h * Rd + r];
}

// ---------------------------------------------------------------------------
// Kernel 1: fused dt path. 4 l per block, 1024 blocks.
// dt = softplus(dt_u @ dt_wT + b), dt_u = u @ xproj_w^T.
// Fast softplus: max(x,0) + __logf(1 + __expf(-|x|)) (no libcall).
// Writes SoA: dtp = dt, usp = u/dt.
// ---------------------------------------------------------------------------
__global__ __launch_bounds__(256) void k_dt(const float* __restrict__ u,
                                            const float* __restrict__ xproj_w,
                                            const float* __restrict__ dt_wT,
                                            const float* __restrict__ dt_b,
                                            float* __restrict__ dtp,
                                            float* __restrict__ usp) {
    __shared__ float u_s[4][Hd];    // 8 KB
    __shared__ float dtu_s[4][Rd];  // 512 B
    const int t = threadIdx.x;
    const int l0 = blockIdx.x * 4;

    #pragma unroll
    for (int i = 0; i < 8; ++i) {
        int idx = t + i * 256;
        ((float*)u_s)[idx] = u[l0 * Hd + idx];
    }
    __syncthreads();

    // einsum1: dt_u[l][r] = sum_h u[l][h]*xproj_w[r][h]; (r,j)=(t>>3,t&7)
    const int r = t >> 3;
    const int j = t & 7;
    float part[4] = {0.f, 0.f, 0.f, 0.f};
    for (int k = 0; k < 64; ++k) {
        float w = xproj_w[r * Hd + k * 8 + j];
        #pragma unroll
        for (int l = 0; l < 4; ++l) part[l] = fmaf(u_s[l][k * 8 + j], w, part[l]);
    }
    #pragma unroll
    for (int off = 1; off < 8; off <<= 1) {
        #pragma unroll
        for (int l = 0; l < 4; ++l) part[l] += __shfl_xor(part[l], off);
    }
    if (j == 0) {
        #pragma unroll
        for (int l = 0; l < 4; ++l) dtu_s[l][r] = part[l];
    }
    __syncthreads();

    // einsum2 + softplus; 2 h per thread
    #pragma unroll
    for (int hb = 0; hb < 2; ++hb) {
        int h = hb * 256 + t;
        float bias = dt_b[h];
        float acc[4] = {bias, bias, bias, bias};
        for (int rr = 0; rr < Rd; ++rr) {
            float w = dt_wT[rr * Hd + h];
            #pragma unroll
            for (int l = 0; l < 4; ++l) acc[l] = fmaf(dtu_s[l][rr], w, acc[l]);
        }
        #pragma unroll
        for (int l = 0; l < 4; ++l) {
            float x = acc[l];
            float e = __expf(-fabsf(x));
            float sp = fmaxf(x, 0.f) + __logf(1.f + e);
            float uv = u_s[l][h];
            float us = uv * __builtin_amdgcn_rcpf(fmaxf(sp, 1e-30f));
            dtp[(l0 + l) * Hd + h] = sp;
            usp[(l0 + l) * Hd + h] = us;
        }
    }
}

// ---------------------------------------------------------------------------
// Per-thread consts: 4 consecutive n (base hnb) of one h. fast when Are
// uniform and Aim arithmetic within the thread's 4 n.
// BA[j] = Bc_j / A_j (ZOH division folded into a constant).
// ---------------------------------------------------------------------------
__device__ __forceinline__ bool load_consts4(const float* __restrict__ A_log,
        const float* __restrict__ A_im, const float* __restrict__ B_param,
        int hnb, float* __restrict__ Are, float* __restrict__ Aim,
        float* __restrict__ BAr, float* __restrict__ BAi) {
    #pragma unroll
    for (int j = 0; j < 4; ++j) {
        int hn = hnb + j;
        Are[j] = -__expf(A_log[hn]);
        Aim[j] = A_im[hn];
        float Br = B_param[2 * hn];
        float Bi = B_param[2 * hn + 1];
        float inv = __builtin_amdgcn_rcpf(Are[j] * Are[j] + Aim[j] * Aim[j]);
        BAr[j] = (Br * Are[j] + Bi * Aim[j]) * inv;
        BAi[j] = (Bi * Are[j] - Br * Aim[j]) * inv;
    }
    float d1 = Aim[1] - Aim[0], d2 = Aim[2] - Aim[1], d3 = Aim[3] - Aim[2];
    return (Are[1] == Are[0]) && (Are[2] == Are[0]) && (Are[3] == Are[0]) &&
           (d1 == d2) && (d2 == d3);
}

// ---------------------------------------------------------------------------
// Kernel 2 (phase 1): chunk-local scan (h0=0), 4 n per thread.
// Block 256 = 64 h x 4 q; grid (NCHUNK, Hd/64) = 2048 blocks (8/CU).
// Emits PS[c][n][h] = (P_re, P_im, S_re, S_im); P = exp(A*sum_dt) exactly.
// ---------------------------------------------------------------------------
__global__ __launch_bounds__(256) void k_chunk(const float* __restrict__ dtp,
        const float* __restrict__ usp,
        const float* __restrict__ A_log, const float* __restrict__ A_im,
        const float* __restrict__ B_param, float4* __restrict__ PS) {
    const int t = threadIdx.x;
    const int q = t & 3;
    const int h = blockIdx.y * 64 + (t >> 2);
    const int c = blockIdx.x;
    const int hnb = h * N2d + q * 4;
    float Are[4], Aim[4], BAr[4], BAi[4];
    const bool fast = load_consts4(A_log, A_im, B_param, hnb, Are, Aim, BAr, BAi);
    float sr[4] = {0.f, 0.f, 0.f, 0.f}, si[4] = {0.f, 0.f, 0.f, 0.f};
    float sdt = 0.f;
    const float* dp = dtp + (size_t)c * CLEN * Hd + h;
    const float* up = usp + (size_t)c * CLEN * Hd + h;
    if (fast) {
        const float Are0 = Are[0], Aimb = Aim[0], dA = Aim[1] - Aim[0];
        #pragma unroll 4
        for (int k = 0; k < CLEN; ++k) {
            float dtv = dp[k * Hd];
            float us  = up[k * Hd];
            sdt += dtv;
            float er = __expf(dtv * Are0);
            float s0, c0, sd, cd;
            __sincosf(dtv * Aimb, &s0, &c0);
            __sincosf(dtv * dA, &sd, &cd);
            float ar = er * c0, ai = er * s0;
            #pragma unroll
            for (int j = 0; j < 4; ++j) {
                float gr = fmaf(ar, us, -us);
                float gi = ai * us;
                float nr = fmaf(ar, sr[j], fmaf(-ai, si[j], fmaf(gr, BAr[j], -gi * BAi[j])));
                float ni = fmaf(ar, si[j], fmaf( ai, sr[j], fmaf(gr, BAi[j],  gi * BAr[j])));
                sr[j] = nr; si[j] = ni;
                if (j < 3) {
                    float tr = fmaf(ar, cd, -ai * sd);
                    ai = fmaf(ai, cd, ar * sd);
                    ar = tr;
                }
            }
        }
        float er = __expf(sdt * Are0);
        float s0, c0, sd, cd;
        __sincosf(sdt * Aimb, &s0, &c0);
        __sincosf(sdt * dA, &sd, &cd);
        float pr = er * c0, pi = er * s0;
        #pragma unroll
        for (int j = 0; j < 4; ++j) {
            PS[c * NCH + (hnb + j - h * N2d) * Hd + h + (h * N2d / N2d) * 0] =
                make_float4(pr, pi, sr[j], si[j]);
            // (index simplifies to c*NCH + (q*4+j)*Hd + h)
            float tr = fmaf(pr, cd, -pi * sd);
            pi = fmaf(pi, cd, pr * sd);
            pr = tr;
        }
    } else {
        for (int k = 0; k < CLEN; ++k) {
            float dtv = dp[k * Hd];
            float us  = up[k * Hd];
            sdt += dtv;
            #pragma unroll
            for (int j = 0; j < 4; ++j) {
                float er = __expf(dtv * Are[j]);
                float s, cc;
                __sincosf(dtv * Aim[j], &s, &cc);
                float ar = er * cc, ai = er * s;
                float gr = fmaf(ar, us, -us);
                float gi = ai * us;
                float nr = fmaf(ar, sr[j], fmaf(-ai, si[j], fmaf(gr, BAr[j], -gi * BAi[j])));
                float ni = fmaf(ar, si[j], fmaf( ai, sr[j], fmaf(gr, BAi[j],  gi * BAr[j])));
                sr[j] = nr; si[j] = ni;
            }
        }
        #pragma unroll
        for (int j = 0; j < 4; ++j) {
            float er = __expf(sdt * Are[j]);
            float s, cc;
            __sincosf(sdt * Aim[j], &s, &cc);
            PS[c * NCH + (q * 4 + j) * Hd + h] = make_float4(er * cc, er * s, sr[j], si[j]);
        }
    }
}

// ---------------------------------------------------------------------------
// Kernel 3 (phase 2): serial combine over 256 chunks -> init state per chunk.
// 8192 threads; loads batched 16 per vmcnt window.
// ---------------------------------------------------------------------------
__global__ __launch_bounds__(256) void k_prefix(const float4* __restrict__ PS,
                                                float2* __restrict__ Ibuf) {
    int idx = blockIdx.x * 256 + threadIdx.x;  // 0..8191 = n*512+h
    float hr = 0.f, hi = 0.f;
    for (int b = 0; b < NCHUNK / 16; ++b) {
        float4 tp[16];
        #pragma unroll
        for (int i = 0; i < 16; ++i) tp[i] = PS[(b * 16 + i) * NCH + idx];
        #pragma unroll
        for (int i = 0; i < 16; ++i) {
            Ibuf[(b * 16 + i) * NCH + idx] = make_float2(hr, hi);
            float nr = fmaf(tp[i].x, hr, fmaf(-tp[i].y, hi, tp[i].z));
            float ni = fmaf(tp[i].x, hi, fmaf( tp[i].y, hr, tp[i].w));
            hr = nr; hi = ni;
        }
    }
}

// ---------------------------------------------------------------------------
// Kernel 4 (phase 3): re-scan with correct init; 4 n per thread; quad-shuffle
// y-reduction; q==0 stores.
// ---------------------------------------------------------------------------
__global__ __launch_bounds__(256) void k_scan(const float* __restrict__ dtp,
        const float* __restrict__ usp,
        const float* __restrict__ A_log, const float* __restrict__ A_im,
        const float* __restrict__ B_param, const float* __restrict__ C_param,
        const float* __restrict__ Dp, const float2* __restrict__ Ibuf,
        float* __restrict__ out) {
    const int t = threadIdx.x;
    const int q = t & 3;
    const int h = blockIdx.y * 64 + (t >> 2);
    const int c = blockIdx.x;
    const int hnb = h * N2d + q * 4;
    float Are[4], Aim[4], BAr[4], BAi[4], Cre[4], Cim[4];
    const bool fast = load_consts4(A_log, A_im, B_param, hnb, Are, Aim, BAr, BAi);
    #pragma unroll
    for (int j = 0; j < 4; ++j) {
        Cre[j] = C_param[2 * (hnb + j)];
        Cim[j] = C_param[2 * (hnb + j) + 1];
    }
    const float Dv = Dp[h];
    float sr[4], si[4];
    #pragma unroll
    for (int j = 0; j < 4; ++j) {
        float2 h0 = Ibuf[c * NCH + (q * 4 + j) * Hd + h];
        sr[j] = h0.x; si[j] = h0.y;
    }
    const float* dp = dtp + (size_t)c * CLEN * Hd + h;
    const float* up = usp + (size_t)c * CLEN * Hd + h;
    float* op = out + (size_t)c * CLEN * Hd + h;
    if (fast) {
        const float Are0 = Are[0], Aimb = Aim[0], dA = Aim[1] - Aim[0];
        #pragma unroll 4
        for (int k = 0; k < CLEN; ++k) {
            float dtv = dp[k * Hd];
            float us  = up[k * Hd];
            float er = __expf(dtv * Are0);
            float s0, c0, sd, cd;
            __sincosf(dtv * Aimb, &s0, &c0);
            __sincosf(dtv * dA, &sd, &cd);
            float ar = er * c0, ai = er * s0;
            float yv = 0.f;
            #pragma unroll
            for (int j = 0; j < 4; ++j) {
                float gr = fmaf(ar, us, -us);
                float gi = ai * us;
                float nr = fmaf(ar, sr[j], fmaf(-ai, si[j], fmaf(gr, BAr[j], -gi * BAi[j])));
                float ni = fmaf(ar, si[j], fmaf( ai, sr[j], fmaf(gr, BAi[j],  gi * BAr[j])));
                sr[j] = nr; si[j] = ni;
                yv = fmaf(nr, Cre[j], fmaf(-ni, Cim[j], yv));
                if (j < 3) {
                    float tr = fmaf(ar, cd, -ai * sd);
                    ai = fmaf(ai, cd, ar * sd);
                    ar = tr;
                }
            }
            yv += __shfl_xor(yv, 1);
            yv += __shfl_xor(yv, 2);
            if (q == 0) op[k * Hd] = fmaf(dtv * us, Dv, yv);
        }
    } else {
        for (int k = 0; k < CLEN; ++k) {
            float dtv = dp[k * Hd];
            float us  = up[k * Hd];
            float yv = 0.f;
            #pragma unroll
            for (int j = 0; j < 4; ++j) {
                float er = __expf(dtv * Are[j]);
                float s, cc;
                __sincosf(dtv * Aim[j], &s, &cc);
                float ar = er * cc, ai = er * s;
                float gr = fmaf(ar, us, -us);
                float gi = ai * us;
                float nr = fmaf(ar, sr[j], fmaf(-ai, si[j], fmaf(gr, BAr[j], -gi * BAi[j])));
                float ni = fmaf(ar, si[j], fmaf( ai, sr[j], fmaf(gr, BAi[j],  gi * BAr[j])));
                sr[j] = nr; si[j] = ni;
                yv = fmaf(nr, Cre[j], fmaf(-ni, Cim[j], yv));
            }
            yv += __shfl_xor(yv, 1);
            yv += __shfl_xor(yv, 2);
            if (q == 0) op[k * Hd] = fmaf(dtv * us, Dv, yv);
        }
    }
}

extern "C" void kernel_launch(void* const* d_in, const int* in_sizes, int n_in,
                              void* d_out, int out_size, void* d_ws, size_t ws_size,
                              hipStream_t stream) {
    const float* u        = (const float*)d_in[0];
    const float* A_log    = (const float*)d_in[1];
    const float* A_im     = (const float*)d_in[2];
    const float* B_param  = (const float*)d_in[3];
    const float* C_param  = (const float*)d_in[4];
    const float* Dp       = (const float*)d_in[5];
    const float* dt_w     = (const float*)d_in[6];
    const float* dt_b     = (const float*)d_in[7];
    const float* xproj_w  = (const float*)d_in[8];

    // ws: dtp[L*H] | usp[L*H] | PS[NCHUNK*NCH f4] | I[NCHUNK*NCH f2] | dt_wT
    float*  dtp  = (float*)d_ws;
    float*  usp  = dtp + (size_t)Ld * Hd;
    float4* PS   = (float4*)(usp + (size_t)Ld * Hd);
    float2* Ibuf = (float2*)(PS + (size_t)NCHUNK * NCH);
    float*  dt_wT = (float*)(Ibuf + (size_t)NCHUNK * NCH);
    float*  out  = (float*)d_out;

    k_tw<<<(Rd * Hd) / 256, 256, 0, stream>>>(dt_w, dt_wT);
    k_dt<<<Ld / 4, 256, 0, stream>>>(u, xproj_w, dt_wT, dt_b, dtp, usp);
    dim3 g2(NCHUNK, Hd / 64);
    k_chunk<<<g2, 256, 0, stream>>>(dtp, usp, A_log, A_im, B_param, PS);
    k_prefix<<<NCH / 256, 256, 0, stream>>>(PS, Ibuf);
    k_scan<<<g2, 256, 0, stream>>>(dtp, usp, A_log, A_im, B_param, C_param,
                                   Dp, Ibuf, out);
}